// Round 7
// baseline (256.818 us; speedup 1.0000x reference)
//
#include <hip/hip_runtime.h>

#define B 2
#define N0 16384
#define HW 16384
#define PADW 130
#define OUTC 256
#define M_ROWS 8192  // B*64*64
#define MAXP 32      // max points/cell tracked (lambda=1 Poisson; P(>32) ~ 0)

typedef short s16x8 __attribute__((ext_vector_type(8)));
typedef float f32x4 __attribute__((ext_vector_type(4)));

__device__ __forceinline__ unsigned short f2bf(float f) {
    union { float f; unsigned int u; } v; v.f = f;
    unsigned int u = v.u;
    return (unsigned short)((u + 0x7fffu + ((u >> 16) & 1u)) >> 16);
}
__device__ __forceinline__ float bf2f(unsigned short h) {
    union { unsigned int u; float f; } v; v.u = ((unsigned int)h) << 16;
    return v.f;
}

// async global->LDS, 16B per lane; LDS dest = wave-uniform base + lane*16
__device__ __forceinline__ void gl_lds16(const void* g, void* l) {
    __builtin_amdgcn_global_load_lds(
        (const __attribute__((address_space(1))) unsigned int*)g,
        (__attribute__((address_space(3))) unsigned int*)l, 16, 0, 0);
}

__device__ __forceinline__ void cell_of(const float* __restrict__ loc, int r, int& ix, int& iy) {
    float lx = loc[r * 2 + 0];
    float ly = loc[r * 2 + 1];
    lx = fminf(fmaxf(lx, -1.f), 1.f);
    ly = fminf(fmaxf(ly, -1.f), 1.f);
    ix = min(max((int)rintf(((lx + 1.f) * 0.5f) * 127.f), 0), 127);
    iy = min(max((int)rintf(((ly + 1.f) * 0.5f) * 127.f), 0), 127);
}

// Build per-cell token lists. One thread per point (131072 total).
__global__ void fill_k(const float* __restrict__ l0, const float* __restrict__ l1,
                       const float* __restrict__ l2, const float* __restrict__ l3,
                       const int* __restrict__ i0, const int* __restrict__ i1,
                       const int* __restrict__ i2, const int* __restrict__ i3,
                       int* __restrict__ cnt32, unsigned short* __restrict__ list) {
    int p = blockIdx.x * 256 + threadIdx.x;
    int j = p >> 15, r = p & 32767;
    const float* loc = j == 0 ? l0 : j == 1 ? l1 : j == 2 ? l2 : l3;
    const int* idx = j == 0 ? i0 : j == 1 ? i1 : j == 2 ? i2 : i3;
    int ix, iy;
    cell_of(loc, r, ix, iy);
    int cidx = (((j << 1) + (r >> 14)) << 14) + iy * 128 + ix;
    int pos = atomicAdd(&cnt32[cidx], 1);
    if (pos < MAXP) list[cidx * MAXP + pos] = (unsigned short)idx[r];
}

// Merged: gather-average per padded cell (blocks < 15844) + weight prep (rest).
__global__ void prep_k(const float* __restrict__ x0, const float* __restrict__ x1,
                       const float* __restrict__ x2, const float* __restrict__ x3,
                       const int* __restrict__ cnt32, const unsigned short* __restrict__ list,
                       unsigned short* __restrict__ mapB,
                       const float* __restrict__ w0, const float* __restrict__ w1,
                       const float* __restrict__ w2, const float* __restrict__ w3,
                       unsigned short* __restrict__ wt) {
    if (blockIdx.x >= 15844) {
        // ---- weight prep: [co][ci][3][3] fp32 -> bf16 [co][(kh*3+kw)*C + ci]
        int i = (blockIdx.x - 15844) * 256 + threadIdx.x;
        if (i >= 2211840) return;
        int j, local;
        if (i < 147456) { j = 0; local = i; }
        else if (i < 442368) { j = 1; local = i - 147456; }
        else if (i < 1032192) { j = 2; local = i - 442368; }
        else { j = 3; local = i - 1032192; }
        const float* w = j == 0 ? w0 : j == 1 ? w1 : j == 2 ? w2 : w3;
        int lc = 6 + j, C = 1 << lc;
        int ci = local & (C - 1);
        int rest = local >> lc;  // co*9 + seg
        int seg = rest % 9, co = rest / 9;
        int kh = seg / 3, kw = seg % 3;
        wt[(size_t)2304 * (C - 64) + local] = f2bf(w[(((co * C) + ci) * 3 + kh) * 3 + kw]);
        return;
    }
    // ---- gather: wave-sliced cells, lanes_per_cell = C/8, 8 channels/lane (16B store)
    int W = (blockIdx.x * 256 + threadIdx.x) >> 6;  // global wave id
    if (W >= 63375) return;
    int lane = threadIdx.x & 63;
    int j, base;
    if (W < 4225) { j = 0; base = 0; }
    else if (W < 12675) { j = 1; base = 4225; }
    else if (W < 29575) { j = 2; base = 12675; }
    else { j = 3; base = 29575; }
    const float* x = j == 0 ? x0 : j == 1 ? x1 : j == 2 ? x2 : x3;
    const int C = 64 << j;
    const int ntok = 16384 >> (2 * j);
    int u = W - base;
    int cellLocal = (u << (3 - j)) + (lane >> (3 + j));  // < 33800
    int sub = lane & ((8 << j) - 1);
    int ch0 = sub * 8;
    int b = cellLocal / 16900;
    int cc = cellLocal - b * 16900;
    int py = cc / 130, px = cc - py * 130;
    unsigned short* dst = mapB + (size_t)33800 * (C - 64) + ((size_t)cellLocal * C) + ch0;
    float a0 = 0.f, a1 = 0.f, a2 = 0.f, a3 = 0.f, a4 = 0.f, a5 = 0.f, a6 = 0.f, a7 = 0.f;
    if (py >= 1 && py <= 128 && px >= 1 && px <= 128) {
        int cidx = (((j << 1) + b) << 14) + (py - 1) * 128 + (px - 1);
        int n = cnt32[cidx];
        float inv = 1.0f / ((float)n + 1e-6f);
        int nn = min(n, MAXP);
        const unsigned short* lst = list + (size_t)cidx * MAXP;
        for (int p = 0; p < nn; p++) {
            int tok = lst[p];
            const float* xr = x + ((size_t)b * ntok + tok) * C + ch0;
            float4 v0 = *(const float4*)xr;
            float4 v1 = *(const float4*)(xr + 4);
            a0 += v0.x; a1 += v0.y; a2 += v0.z; a3 += v0.w;
            a4 += v1.x; a5 += v1.y; a6 += v1.z; a7 += v1.w;
        }
        a0 *= inv; a1 *= inv; a2 *= inv; a3 *= inv;
        a4 *= inv; a5 *= inv; a6 *= inv; a7 *= inv;
    }
    uint4 o;
    o.x = (unsigned int)f2bf(a0) | ((unsigned int)f2bf(a1) << 16);
    o.y = (unsigned int)f2bf(a2) | ((unsigned int)f2bf(a3) << 16);
    o.z = (unsigned int)f2bf(a4) | ((unsigned int)f2bf(a5) << 16);
    o.w = (unsigned int)f2bf(a6) | ((unsigned int)f2bf(a7) << 16);
    *(uint4*)dst = o;
}

// Split-K implicit-GEMM conv. 256 threads, 2x2 waves of 64x64 tiles (r5 structure).
// A: double-buffered LDS via global_load_lds. B: direct global->register, ping-pong
// prefetched one K-step ahead (wt is L2-resident; no intra-block B reuse -> skip LDS).
// 8 chunk-slots (z): j={3,3,3,3,2,2,1,0}; slot z writes bf16 partial P[z].
__global__ __launch_bounds__(256) void conv_mfma(const unsigned short* __restrict__ mapB,
                                                 const unsigned short* __restrict__ wt,
                                                 unsigned short* __restrict__ P) {
    __shared__ unsigned short As[2][128][32];  // 16 KB total
    const int t = threadIdx.x;
    const int lane = t & 63;
    const int w = t >> 6;
    const int wm = w >> 1, wn = w & 1;
    const int z = blockIdx.z;
    const int j = (z < 4) ? 3 : (z < 6) ? 2 : (z == 6) ? 1 : 0;
    const int lc = 6 + j;
    const int C = 1 << lc;
    const int K = 9 * C;
    const int s0 = (z < 4) ? z * 36 : (z == 5 ? 36 : 0);
    const int s1 = s0 + (j == 0 ? 18 : 36);  // always even length
    const unsigned short* mapBj = mapB + (size_t)33800 * (C - 64);
    const unsigned short* wtj = wt + (size_t)2304 * (C - 64);
    unsigned short* Pz = P + (size_t)z * M_ROWS * OUTC;
    const int mt = blockIdx.x, nt = blockIdx.y;

    // A staging: lane -> (row lr, 16B quarter lq); each wave stages rows w*32..+32
    const int lr = lane >> 2, lq = lane & 3;
    const unsigned short* pA[2];
#pragma unroll
    for (int i = 0; i < 2; i++) {
        int r = w * 32 + i * 16 + lr;
        int s = mt * 128 + r;
        int b = s >> 12, rem = s & 4095, oh = rem >> 6, ow = rem & 63;
        pA[i] = mapBj + (size_t)((b * PADW + 2 * oh) * PADW + 2 * ow) * C + lq * 8;
    }

    const int r16 = lane & 15, kg = lane >> 4;
    // B fragment row pointers (per ni): direct global loads, 16B per lane
    const unsigned short* pBrow[4];
#pragma unroll
    for (int ni = 0; ni < 4; ni++)
        pBrow[ni] = wtj + (size_t)(nt * 128 + wn * 64 + ni * 16 + r16) * K + kg * 8;

    // incremental K-offsets: k = s*32
    int k0 = s0 << 5;
    int ci0 = k0 & (C - 1);
    int seg0 = k0 >> lc;
    int kh = seg0 / 3, kw = seg0 - 3 * kh;
    int offA = (kh * PADW + kw) * C + ci0;
    int offB = k0;

    // preload step s0: A -> As[0], B -> bA
    gl_lds16(pA[0] + offA, &As[0][w * 32][0]);
    gl_lds16(pA[1] + offA, &As[0][w * 32 + 16][0]);
    s16x8 bA[4], bB[4];
#pragma unroll
    for (int ni = 0; ni < 4; ni++) bA[ni] = *(const s16x8*)(pBrow[ni] + offB);

    f32x4 acc[4][4];
#pragma unroll
    for (int mi = 0; mi < 4; mi++)
#pragma unroll
        for (int ni = 0; ni < 4; ni++) acc[mi][ni] = (f32x4){0.f, 0.f, 0.f, 0.f};

#define ADVANCE() do { ci0 += 32; offA += 32; offB += 32; \
        if (ci0 == C) { ci0 = 0; kw++; if (kw == 3) { kw = 0; offA += (PADW - 3) * C; } } } while (0)

#define COMPUTE(BUF, BREG) do { \
        s16x8 a0 = *(const s16x8*)&As[BUF][wm * 64 + 0 * 16 + r16][kg * 8]; \
        s16x8 a1 = *(const s16x8*)&As[BUF][wm * 64 + 1 * 16 + r16][kg * 8]; \
        s16x8 a2 = *(const s16x8*)&As[BUF][wm * 64 + 2 * 16 + r16][kg * 8]; \
        s16x8 a3 = *(const s16x8*)&As[BUF][wm * 64 + 3 * 16 + r16][kg * 8]; \
        acc[0][0] = __builtin_amdgcn_mfma_f32_16x16x32_bf16(a0, BREG[0], acc[0][0], 0, 0, 0); \
        acc[0][1] = __builtin_amdgcn_mfma_f32_16x16x32_bf16(a0, BREG[1], acc[0][1], 0, 0, 0); \
        acc[0][2] = __builtin_amdgcn_mfma_f32_16x16x32_bf16(a0, BREG[2], acc[0][2], 0, 0, 0); \
        acc[0][3] = __builtin_amdgcn_mfma_f32_16x16x32_bf16(a0, BREG[3], acc[0][3], 0, 0, 0); \
        acc[1][0] = __builtin_amdgcn_mfma_f32_16x16x32_bf16(a1, BREG[0], acc[1][0], 0, 0, 0); \
        acc[1][1] = __builtin_amdgcn_mfma_f32_16x16x32_bf16(a1, BREG[1], acc[1][1], 0, 0, 0); \
        acc[1][2] = __builtin_amdgcn_mfma_f32_16x16x32_bf16(a1, BREG[2], acc[1][2], 0, 0, 0); \
        acc[1][3] = __builtin_amdgcn_mfma_f32_16x16x32_bf16(a1, BREG[3], acc[1][3], 0, 0, 0); \
        acc[2][0] = __builtin_amdgcn_mfma_f32_16x16x32_bf16(a2, BREG[0], acc[2][0], 0, 0, 0); \
        acc[2][1] = __builtin_amdgcn_mfma_f32_16x16x32_bf16(a2, BREG[1], acc[2][1], 0, 0, 0); \
        acc[2][2] = __builtin_amdgcn_mfma_f32_16x16x32_bf16(a2, BREG[2], acc[2][2], 0, 0, 0); \
        acc[2][3] = __builtin_amdgcn_mfma_f32_16x16x32_bf16(a2, BREG[3], acc[2][3], 0, 0, 0); \
        acc[3][0] = __builtin_amdgcn_mfma_f32_16x16x32_bf16(a3, BREG[0], acc[3][0], 0, 0, 0); \
        acc[3][1] = __builtin_amdgcn_mfma_f32_16x16x32_bf16(a3, BREG[1], acc[3][1], 0, 0, 0); \
        acc[3][2] = __builtin_amdgcn_mfma_f32_16x16x32_bf16(a3, BREG[2], acc[3][2], 0, 0, 0); \
        acc[3][3] = __builtin_amdgcn_mfma_f32_16x16x32_bf16(a3, BREG[3], acc[3][3], 0, 0, 0); \
    } while (0)

    for (int s = s0; s < s1; s += 2) {
        // ---- half 1: compute on As[0]/bA, prefetch s+1 into As[1]/bB
        ADVANCE();  // offsets -> s+1
        __syncthreads();  // drains As[0] DMA + bA loads (issued a full phase ago)
        if (s + 1 < s1) {
            gl_lds16(pA[0] + offA, &As[1][w * 32][0]);
            gl_lds16(pA[1] + offA, &As[1][w * 32 + 16][0]);
#pragma unroll
            for (int ni = 0; ni < 4; ni++) bB[ni] = *(const s16x8*)(pBrow[ni] + offB);
        }
        COMPUTE(0, bA);
        // ---- half 2: compute on As[1]/bB, prefetch s+2 into As[0]/bA
        ADVANCE();  // offsets -> s+2
        __syncthreads();
        if (s + 2 < s1) {
            gl_lds16(pA[0] + offA, &As[0][w * 32][0]);
            gl_lds16(pA[1] + offA, &As[0][w * 32 + 16][0]);
#pragma unroll
            for (int ni = 0; ni < 4; ni++) bA[ni] = *(const s16x8*)(pBrow[ni] + offB);
        }
        COMPUTE(1, bB);
    }
#undef ADVANCE
#undef COMPUTE

    // C/D layout: col = lane&15, row = (lane>>4)*4 + reg
    const int rg = lane >> 4, c16 = lane & 15;
#pragma unroll
    for (int mi = 0; mi < 4; mi++)
#pragma unroll
        for (int ni = 0; ni < 4; ni++)
#pragma unroll
            for (int reg = 0; reg < 4; reg++) {
                int row = mt * 128 + wm * 64 + mi * 16 + rg * 4 + reg;
                int col = nt * 128 + wn * 64 + ni * 16 + c16;
                Pz[(size_t)row * OUTC + col] = f2bf(acc[mi][ni][reg]);
            }
}

// Channel stats on COMBINED per-branch values (correct split-K sumsq).
// 256 blocks x 32 rows; block-reduce then atomicAdd into branchAcc[4][512].
__global__ void statsC_k(const unsigned short* __restrict__ P, float* __restrict__ branchAcc) {
    __shared__ float red_s[8][256], red_ss[8][256];  // 16 KB
    int bi = blockIdx.x;  // 256
    int t = threadIdx.x;
    int cg = t & 31, rt = t >> 5;
    float s[4][8], ss[4][8];
#pragma unroll
    for (int j = 0; j < 4; j++)
#pragma unroll
        for (int k = 0; k < 8; k++) { s[j][k] = 0.f; ss[j][k] = 0.f; }
    for (int r = rt; r < 32; r += 8) {
        size_t row = (size_t)bi * 32 + r;
        const unsigned short* p = P + row * OUTC + cg * 8;
        float v[4][8];
#pragma unroll
        for (int j = 0; j < 4; j++)
#pragma unroll
            for (int k = 0; k < 8; k++) v[j][k] = 0.f;
#pragma unroll
        for (int zz = 0; zz < 8; zz++) {
            int j = (zz < 4) ? 3 : (zz < 6) ? 2 : (zz == 6) ? 1 : 0;
            uint4 u = *(const uint4*)(p + (size_t)zz * M_ROWS * OUTC);
            v[j][0] += bf2f((unsigned short)(u.x & 0xffff));
            v[j][1] += bf2f((unsigned short)(u.x >> 16));
            v[j][2] += bf2f((unsigned short)(u.y & 0xffff));
            v[j][3] += bf2f((unsigned short)(u.y >> 16));
            v[j][4] += bf2f((unsigned short)(u.z & 0xffff));
            v[j][5] += bf2f((unsigned short)(u.z >> 16));
            v[j][6] += bf2f((unsigned short)(u.w & 0xffff));
            v[j][7] += bf2f((unsigned short)(u.w >> 16));
        }
#pragma unroll
        for (int j = 0; j < 4; j++)
#pragma unroll
            for (int k = 0; k < 8; k++) {
                s[j][k] += v[j][k];
                ss[j][k] += v[j][k] * v[j][k];
            }
    }
    for (int j = 0; j < 4; j++) {
#pragma unroll
        for (int k = 0; k < 8; k++) {
            red_s[rt][cg * 8 + k] = s[j][k];
            red_ss[rt][cg * 8 + k] = ss[j][k];
        }
        __syncthreads();
        float S = 0.f, SS = 0.f;
#pragma unroll
        for (int r = 0; r < 8; r++) { S += red_s[r][t]; SS += red_ss[r][t]; }
        atomicAdd(&branchAcc[j * 512 + t], S);
        atomicAdd(&branchAcc[j * 512 + 256 + t], SS);
        __syncthreads();
    }
}

// fused: inline BN-fold from branchAcc + affine + 8-slot sum + NHWC->NCHW transpose
__global__ void out_k(const unsigned short* __restrict__ P, const float* __restrict__ branchAcc,
                      const float* __restrict__ g0, const float* __restrict__ g1,
                      const float* __restrict__ g2, const float* __restrict__ g3,
                      const float* __restrict__ b0, const float* __restrict__ b1,
                      const float* __restrict__ b2, const float* __restrict__ b3,
                      float* __restrict__ out) {
    __shared__ float tile[64][132];
    int oh = blockIdx.x, ct = blockIdx.y, b = blockIdx.z;  // 64, 2, 2
    int t = threadIdx.x;
    int cg = t & 31, rt = t >> 5;  // 4 channels each, 8 row-threads
    int c0 = ct * 128 + cg * 4;
    float sc[4][4], sh[4];
#pragma unroll
    for (int k = 0; k < 4; k++) {
        int c = c0 + k;
        float shk = 0.f;
#pragma unroll
        for (int jj = 0; jj < 4; jj++) {
            const float* gamma = jj == 0 ? g0 : jj == 1 ? g1 : jj == 2 ? g2 : g3;
            const float* beta = jj == 0 ? b0 : jj == 1 ? b1 : jj == 2 ? b2 : b3;
            float sum = branchAcc[jj * 512 + c];
            float sumsq = branchAcc[jj * 512 + 256 + c];
            float mean = sum * (1.f / 8192.f);
            float var = sumsq * (1.f / 8192.f) - mean * mean;
            float rs = rsqrtf(var + 1e-5f);
            float scv = gamma[c] * rs;
            sc[jj][k] = scv;
            shk += beta[c] - mean * scv;
        }
        sh[k] = shk;
    }
#pragma unroll
    for (int it = 0; it < 8; it++) {
        int ow = rt * 8 + it;
        size_t row = (size_t)b * 4096 + oh * 64 + ow;
        const unsigned short* p = P + row * OUTC + c0;
        float a3k[4], a2k[4], a1k[4], a0k[4];
#pragma unroll
        for (int k = 0; k < 4; k++) { a3k[k] = a2k[k] = a1k[k] = a0k[k] = 0.f; }
#pragma unroll
        for (int zz = 0; zz < 8; zz++) {
            ushort4 u = *(const ushort4*)(p + (size_t)zz * M_ROWS * OUTC);
            float* a = zz < 4 ? a3k : zz < 6 ? a2k : (zz == 6 ? a1k : a0k);
            a[0] += bf2f(u.x);
            a[1] += bf2f(u.y);
            a[2] += bf2f(u.z);
            a[3] += bf2f(u.w);
        }
#pragma unroll
        for (int k = 0; k < 4; k++)
            tile[ow][cg * 4 + k] = sh[k] + a3k[k] * sc[3][k] + a2k[k] * sc[2][k] +
                                   a1k[k] * sc[1][k] + a0k[k] * sc[0][k];
    }
    __syncthreads();
    int owq = t & 15, cp = t >> 4;
#pragma unroll
    for (int pass = 0; pass < 8; pass++) {
        int c = pass * 16 + cp;
        float4 v;
        v.x = tile[owq * 4 + 0][c];
        v.y = tile[owq * 4 + 1][c];
        v.z = tile[owq * 4 + 2][c];
        v.w = tile[owq * 4 + 3][c];
        *(float4*)(out + (((size_t)b * OUTC + ct * 128 + c) * 64 + oh) * 64 + owq * 4) = v;
    }
}

extern "C" void kernel_launch(void* const* d_in, const int* in_sizes, int n_in,
                              void* d_out, int out_size, void* d_ws, size_t ws_size,
                              hipStream_t stream) {
    char* ws = (char*)d_ws;
    size_t off = 0;
    auto alloc = [&](size_t bytes) {
        void* p = ws + off;
        off = (off + bytes + 255) & ~(size_t)255;
        return p;
    };
    unsigned short* P = (unsigned short*)alloc((size_t)8 * M_ROWS * OUTC * 2);   // 33.6 MB
    unsigned short* wt = (unsigned short*)alloc((size_t)2304 * 960 * 2);         // 4.4 MB
    unsigned short* mapB = (unsigned short*)alloc((size_t)33800 * 960 * 2);      // 64.9 MB
    int* cnt32 = (int*)alloc((size_t)4 * 2 * HW * 4);                            // 0.5 MB
    float* branchAcc = (float*)alloc((size_t)4 * 512 * 4);                       // contiguous w/ cnt32
    unsigned short* list = (unsigned short*)alloc((size_t)4 * 2 * HW * MAXP * 2);// 8 MB

    hipMemsetAsync(cnt32, 0, (size_t)4 * 2 * HW * 4 + 4 * 512 * 4, stream);  // cnt32 + branchAcc

    fill_k<<<512, 256, 0, stream>>>(
        (const float*)d_in[1], (const float*)d_in[7], (const float*)d_in[13],
        (const float*)d_in[19],
        (const int*)d_in[2], (const int*)d_in[8], (const int*)d_in[14],
        (const int*)d_in[20], cnt32, list);
    prep_k<<<15844 + 8640, 256, 0, stream>>>(
        (const float*)d_in[0], (const float*)d_in[6], (const float*)d_in[12],
        (const float*)d_in[18], cnt32, list, mapB,
        (const float*)d_in[3], (const float*)d_in[9], (const float*)d_in[15],
        (const float*)d_in[21], wt);
    conv_mfma<<<dim3(64, 2, 8), 256, 0, stream>>>(mapB, wt, P);
    statsC_k<<<256, 256, 0, stream>>>(P, branchAcc);
    out_k<<<dim3(64, 2, 2), 256, 0, stream>>>(P, branchAcc,
        (const float*)d_in[4], (const float*)d_in[10], (const float*)d_in[16],
        (const float*)d_in[22],
        (const float*)d_in[5], (const float*)d_in[11], (const float*)d_in[17],
        (const float*)d_in[23], (float*)d_out);
}

// Round 8
// 228.327 us; speedup vs baseline: 1.1248x; 1.1248x over previous
//
#include <hip/hip_runtime.h>

#define B 2
#define N0 16384
#define HW 16384
#define PADW 130
#define OUTC 256
#define M_ROWS 8192  // B*64*64
#define MAXP 32      // max points/cell tracked (lambda=1 Poisson; P(>32) ~ 0)

typedef short s16x8 __attribute__((ext_vector_type(8)));
typedef float f32x4 __attribute__((ext_vector_type(4)));

__device__ __forceinline__ unsigned short f2bf(float f) {
    union { float f; unsigned int u; } v; v.f = f;
    unsigned int u = v.u;
    return (unsigned short)((u + 0x7fffu + ((u >> 16) & 1u)) >> 16);
}
__device__ __forceinline__ float bf2f(unsigned short h) {
    union { unsigned int u; float f; } v; v.u = ((unsigned int)h) << 16;
    return v.f;
}

// async global->LDS, 16B per lane; LDS dest = wave-uniform base + lane*16
__device__ __forceinline__ void gl_lds16(const void* g, void* l) {
    __builtin_amdgcn_global_load_lds(
        (const __attribute__((address_space(1))) unsigned int*)g,
        (__attribute__((address_space(3))) unsigned int*)l, 16, 0, 0);
}

__device__ __forceinline__ void cell_of(const float* __restrict__ loc, int r, int& ix, int& iy) {
    float lx = loc[r * 2 + 0];
    float ly = loc[r * 2 + 1];
    lx = fminf(fmaxf(lx, -1.f), 1.f);
    ly = fminf(fmaxf(ly, -1.f), 1.f);
    ix = min(max((int)rintf(((lx + 1.f) * 0.5f) * 127.f), 0), 127);
    iy = min(max((int)rintf(((ly + 1.f) * 0.5f) * 127.f), 0), 127);
}

// Build per-cell token lists. One thread per point (131072 total).
__global__ void fill_k(const float* __restrict__ l0, const float* __restrict__ l1,
                       const float* __restrict__ l2, const float* __restrict__ l3,
                       const int* __restrict__ i0, const int* __restrict__ i1,
                       const int* __restrict__ i2, const int* __restrict__ i3,
                       int* __restrict__ cnt32, unsigned short* __restrict__ list) {
    int p = blockIdx.x * 256 + threadIdx.x;
    int j = p >> 15, r = p & 32767;
    const float* loc = j == 0 ? l0 : j == 1 ? l1 : j == 2 ? l2 : l3;
    const int* idx = j == 0 ? i0 : j == 1 ? i1 : j == 2 ? i2 : i3;
    int ix, iy;
    cell_of(loc, r, ix, iy);
    int cidx = (((j << 1) + (r >> 14)) << 14) + iy * 128 + ix;
    int pos = atomicAdd(&cnt32[cidx], 1);
    if (pos < MAXP) list[cidx * MAXP + pos] = (unsigned short)idx[r];
}

// Merged: gather-average per padded cell (blocks < 15844) + weight prep (rest).
__global__ void prep_k(const float* __restrict__ x0, const float* __restrict__ x1,
                       const float* __restrict__ x2, const float* __restrict__ x3,
                       const int* __restrict__ cnt32, const unsigned short* __restrict__ list,
                       unsigned short* __restrict__ mapB,
                       const float* __restrict__ w0, const float* __restrict__ w1,
                       const float* __restrict__ w2, const float* __restrict__ w3,
                       unsigned short* __restrict__ wt) {
    if (blockIdx.x >= 15844) {
        // ---- weight prep: [co][ci][3][3] fp32 -> bf16 [co][(kh*3+kw)*C + ci]
        int i = (blockIdx.x - 15844) * 256 + threadIdx.x;
        if (i >= 2211840) return;
        int j, local;
        if (i < 147456) { j = 0; local = i; }
        else if (i < 442368) { j = 1; local = i - 147456; }
        else if (i < 1032192) { j = 2; local = i - 442368; }
        else { j = 3; local = i - 1032192; }
        const float* w = j == 0 ? w0 : j == 1 ? w1 : j == 2 ? w2 : w3;
        int lc = 6 + j, C = 1 << lc;
        int ci = local & (C - 1);
        int rest = local >> lc;  // co*9 + seg
        int seg = rest % 9, co = rest / 9;
        int kh = seg / 3, kw = seg % 3;
        wt[(size_t)2304 * (C - 64) + local] = f2bf(w[(((co * C) + ci) * 3 + kh) * 3 + kw]);
        return;
    }
    // ---- gather: wave-sliced cells, lanes_per_cell = C/8, 8 channels/lane (16B store)
    int W = (blockIdx.x * 256 + threadIdx.x) >> 6;  // global wave id
    if (W >= 63375) return;
    int lane = threadIdx.x & 63;
    int j, base;
    if (W < 4225) { j = 0; base = 0; }
    else if (W < 12675) { j = 1; base = 4225; }
    else if (W < 29575) { j = 2; base = 12675; }
    else { j = 3; base = 29575; }
    const float* x = j == 0 ? x0 : j == 1 ? x1 : j == 2 ? x2 : x3;
    const int C = 64 << j;
    const int ntok = 16384 >> (2 * j);
    int u = W - base;
    int cellLocal = (u << (3 - j)) + (lane >> (3 + j));  // < 33800
    int sub = lane & ((8 << j) - 1);
    int ch0 = sub * 8;
    int b = cellLocal / 16900;
    int cc = cellLocal - b * 16900;
    int py = cc / 130, px = cc - py * 130;
    unsigned short* dst = mapB + (size_t)33800 * (C - 64) + ((size_t)cellLocal * C) + ch0;
    float a0 = 0.f, a1 = 0.f, a2 = 0.f, a3 = 0.f, a4 = 0.f, a5 = 0.f, a6 = 0.f, a7 = 0.f;
    if (py >= 1 && py <= 128 && px >= 1 && px <= 128) {
        int cidx = (((j << 1) + b) << 14) + (py - 1) * 128 + (px - 1);
        int n = cnt32[cidx];
        float inv = 1.0f / ((float)n + 1e-6f);
        int nn = min(n, MAXP);
        const unsigned short* lst = list + (size_t)cidx * MAXP;
        for (int p = 0; p < nn; p++) {
            int tok = lst[p];
            const float* xr = x + ((size_t)b * ntok + tok) * C + ch0;
            float4 v0 = *(const float4*)xr;
            float4 v1 = *(const float4*)(xr + 4);
            a0 += v0.x; a1 += v0.y; a2 += v0.z; a3 += v0.w;
            a4 += v1.x; a5 += v1.y; a6 += v1.z; a7 += v1.w;
        }
        a0 *= inv; a1 *= inv; a2 *= inv; a3 *= inv;
        a4 *= inv; a5 *= inv; a6 *= inv; a7 *= inv;
    }
    uint4 o;
    o.x = (unsigned int)f2bf(a0) | ((unsigned int)f2bf(a1) << 16);
    o.y = (unsigned int)f2bf(a2) | ((unsigned int)f2bf(a3) << 16);
    o.z = (unsigned int)f2bf(a4) | ((unsigned int)f2bf(a5) << 16);
    o.w = (unsigned int)f2bf(a6) | ((unsigned int)f2bf(a7) << 16);
    *(uint4*)dst = o;
}

// Split-K implicit-GEMM conv (r5-proven structure: all staging via global_load_lds DMA,
// double-buffered LDS, 256 threads, 2x2 waves of 64x64). XCD-aware 1D swizzle: both
// nt-halves of an (mt,z) pair land on the same XCD, adjacent in dispatch order, so the
// shared A-slice (and same-z B-slice) hits that XCD's L2 instead of refetching HBM.
__global__ __launch_bounds__(256, 4) void conv_mfma(const unsigned short* __restrict__ mapB,
                                                    const unsigned short* __restrict__ wt,
                                                    unsigned short* __restrict__ P) {
    __shared__ unsigned short As[2][128][32];  // 16 KB
    __shared__ unsigned short Bs[2][128][32];  // 16 KB
    const int t = threadIdx.x;
    const int lane = t & 63;
    const int w = t >> 6;
    const int wm = w >> 1, wn = w & 1;
    // swizzled decode
    const int bid = blockIdx.x;
    const int xcd = bid & 7;
    const int nt = (bid >> 3) & 1;
    const int pairIdx = (bid >> 4) * 8 + xcd;  // 0..511, spread over z per XCD
    const int mt = pairIdx & 63;
    const int z = pairIdx >> 6;
    const int j = (z < 4) ? 3 : (z < 6) ? 2 : (z == 6) ? 1 : 0;
    const int lc = 6 + j;
    const int C = 1 << lc;
    const int K = 9 * C;
    const int s0 = (z < 4) ? z * 36 : (z == 5 ? 36 : 0);
    const int s1 = s0 + (j == 0 ? 18 : 36);
    const unsigned short* mapBj = mapB + (size_t)33800 * (C - 64);
    const unsigned short* wtj = wt + (size_t)2304 * (C - 64);
    unsigned short* Pz = P + (size_t)z * M_ROWS * OUTC;

    // staging sources: lane -> (row lr, 16B quarter lq); 2 A rows + 2 B rows per lane
    const int lr = lane >> 2, lq = lane & 3;
    const unsigned short* pA[2];
    const unsigned short* pB[2];
#pragma unroll
    for (int i = 0; i < 2; i++) {
        int r = w * 32 + i * 16 + lr;
        int s = mt * 128 + r;
        int b = s >> 12, rem = s & 4095, oh = rem >> 6, ow = rem & 63;
        pA[i] = mapBj + (size_t)((b * PADW + 2 * oh) * PADW + 2 * ow) * C + lq * 8;
        pB[i] = wtj + (size_t)(nt * 128 + r) * K + lq * 8;
    }

    // incremental K-offsets: k = s*32
    int k0 = s0 << 5;
    int seg0 = k0 >> lc;
    int ci0 = k0 & (C - 1);
    int kh = seg0 / 3, kw = seg0 - 3 * kh;
    int offA = (kh * PADW + kw) * C + ci0;
    int offB = k0;

    // preload buffer 0 for step s0
    gl_lds16(pA[0] + offA, &As[0][w * 32][0]);
    gl_lds16(pA[1] + offA, &As[0][w * 32 + 16][0]);
    gl_lds16(pB[0] + offB, &Bs[0][w * 32][0]);
    gl_lds16(pB[1] + offB, &Bs[0][w * 32 + 16][0]);

    f32x4 acc[4][4];
#pragma unroll
    for (int mi = 0; mi < 4; mi++)
#pragma unroll
        for (int ni = 0; ni < 4; ni++) acc[mi][ni] = (f32x4){0.f, 0.f, 0.f, 0.f};

    const int r16 = lane & 15, kg = lane >> 4;
    int buf = 0;
    for (int s = s0; s < s1; s++) {
        // advance offsets to step s+1
        ci0 += 32; offA += 32; offB += 32;
        if (ci0 == C) {
            ci0 = 0; kw++;
            if (kw == 3) { kw = 0; offA += (PADW - 3) * C; }
        }
        __syncthreads();  // drains prior prefetch (issued a full phase ago)
        if (s + 1 < s1) {
            int nb = buf ^ 1;
            gl_lds16(pA[0] + offA, &As[nb][w * 32][0]);
            gl_lds16(pA[1] + offA, &As[nb][w * 32 + 16][0]);
            gl_lds16(pB[0] + offB, &Bs[nb][w * 32][0]);
            gl_lds16(pB[1] + offB, &Bs[nb][w * 32 + 16][0]);
        }
        s16x8 a0 = *(const s16x8*)&As[buf][wm * 64 + 0 * 16 + r16][kg * 8];
        s16x8 a1 = *(const s16x8*)&As[buf][wm * 64 + 1 * 16 + r16][kg * 8];
        s16x8 a2 = *(const s16x8*)&As[buf][wm * 64 + 2 * 16 + r16][kg * 8];
        s16x8 a3 = *(const s16x8*)&As[buf][wm * 64 + 3 * 16 + r16][kg * 8];
        s16x8 b0 = *(const s16x8*)&Bs[buf][wn * 64 + 0 * 16 + r16][kg * 8];
        s16x8 b1 = *(const s16x8*)&Bs[buf][wn * 64 + 1 * 16 + r16][kg * 8];
        s16x8 b2 = *(const s16x8*)&Bs[buf][wn * 64 + 2 * 16 + r16][kg * 8];
        s16x8 b3 = *(const s16x8*)&Bs[buf][wn * 64 + 3 * 16 + r16][kg * 8];
        acc[0][0] = __builtin_amdgcn_mfma_f32_16x16x32_bf16(a0, b0, acc[0][0], 0, 0, 0);
        acc[0][1] = __builtin_amdgcn_mfma_f32_16x16x32_bf16(a0, b1, acc[0][1], 0, 0, 0);
        acc[0][2] = __builtin_amdgcn_mfma_f32_16x16x32_bf16(a0, b2, acc[0][2], 0, 0, 0);
        acc[0][3] = __builtin_amdgcn_mfma_f32_16x16x32_bf16(a0, b3, acc[0][3], 0, 0, 0);
        acc[1][0] = __builtin_amdgcn_mfma_f32_16x16x32_bf16(a1, b0, acc[1][0], 0, 0, 0);
        acc[1][1] = __builtin_amdgcn_mfma_f32_16x16x32_bf16(a1, b1, acc[1][1], 0, 0, 0);
        acc[1][2] = __builtin_amdgcn_mfma_f32_16x16x32_bf16(a1, b2, acc[1][2], 0, 0, 0);
        acc[1][3] = __builtin_amdgcn_mfma_f32_16x16x32_bf16(a1, b3, acc[1][3], 0, 0, 0);
        acc[2][0] = __builtin_amdgcn_mfma_f32_16x16x32_bf16(a2, b0, acc[2][0], 0, 0, 0);
        acc[2][1] = __builtin_amdgcn_mfma_f32_16x16x32_bf16(a2, b1, acc[2][1], 0, 0, 0);
        acc[2][2] = __builtin_amdgcn_mfma_f32_16x16x32_bf16(a2, b2, acc[2][2], 0, 0, 0);
        acc[2][3] = __builtin_amdgcn_mfma_f32_16x16x32_bf16(a2, b3, acc[2][3], 0, 0, 0);
        acc[3][0] = __builtin_amdgcn_mfma_f32_16x16x32_bf16(a3, b0, acc[3][0], 0, 0, 0);
        acc[3][1] = __builtin_amdgcn_mfma_f32_16x16x32_bf16(a3, b1, acc[3][1], 0, 0, 0);
        acc[3][2] = __builtin_amdgcn_mfma_f32_16x16x32_bf16(a3, b2, acc[3][2], 0, 0, 0);
        acc[3][3] = __builtin_amdgcn_mfma_f32_16x16x32_bf16(a3, b3, acc[3][3], 0, 0, 0);
        buf ^= 1;
    }

    // C/D layout: col = lane&15, row = (lane>>4)*4 + reg
    const int rg = lane >> 4, c16 = lane & 15;
#pragma unroll
    for (int mi = 0; mi < 4; mi++)
#pragma unroll
        for (int ni = 0; ni < 4; ni++)
#pragma unroll
            for (int reg = 0; reg < 4; reg++) {
                int row = mt * 128 + wm * 64 + mi * 16 + rg * 4 + reg;
                int col = nt * 128 + wn * 64 + ni * 16 + c16;
                Pz[(size_t)row * OUTC + col] = f2bf(acc[mi][ni][reg]);
            }
}

// Channel stats on COMBINED per-branch values (correct split-K sumsq).
// 512 blocks x 16 rows; block-reduce then atomicAdd into branchAcc[4][512].
__global__ void statsC_k(const unsigned short* __restrict__ P, float* __restrict__ branchAcc) {
    __shared__ float red_s[8][256], red_ss[8][256];  // 16 KB
    int bi = blockIdx.x;  // 512
    int t = threadIdx.x;
    int cg = t & 31, rt = t >> 5;
    float s[4][8], ss[4][8];
#pragma unroll
    for (int j = 0; j < 4; j++)
#pragma unroll
        for (int k = 0; k < 8; k++) { s[j][k] = 0.f; ss[j][k] = 0.f; }
    for (int r = rt; r < 16; r += 8) {
        size_t row = (size_t)bi * 16 + r;
        const unsigned short* p = P + row * OUTC + cg * 8;
        float v[4][8];
#pragma unroll
        for (int j = 0; j < 4; j++)
#pragma unroll
            for (int k = 0; k < 8; k++) v[j][k] = 0.f;
#pragma unroll
        for (int zz = 0; zz < 8; zz++) {
            int j = (zz < 4) ? 3 : (zz < 6) ? 2 : (zz == 6) ? 1 : 0;
            uint4 u = *(const uint4*)(p + (size_t)zz * M_ROWS * OUTC);
            v[j][0] += bf2f((unsigned short)(u.x & 0xffff));
            v[j][1] += bf2f((unsigned short)(u.x >> 16));
            v[j][2] += bf2f((unsigned short)(u.y & 0xffff));
            v[j][3] += bf2f((unsigned short)(u.y >> 16));
            v[j][4] += bf2f((unsigned short)(u.z & 0xffff));
            v[j][5] += bf2f((unsigned short)(u.z >> 16));
            v[j][6] += bf2f((unsigned short)(u.w & 0xffff));
            v[j][7] += bf2f((unsigned short)(u.w >> 16));
        }
#pragma unroll
        for (int j = 0; j < 4; j++)
#pragma unroll
            for (int k = 0; k < 8; k++) {
                s[j][k] += v[j][k];
                ss[j][k] += v[j][k] * v[j][k];
            }
    }
    for (int j = 0; j < 4; j++) {
#pragma unroll
        for (int k = 0; k < 8; k++) {
            red_s[rt][cg * 8 + k] = s[j][k];
            red_ss[rt][cg * 8 + k] = ss[j][k];
        }
        __syncthreads();
        float S = 0.f, SS = 0.f;
#pragma unroll
        for (int r = 0; r < 8; r++) { S += red_s[r][t]; SS += red_ss[r][t]; }
        atomicAdd(&branchAcc[j * 512 + t], S);
        atomicAdd(&branchAcc[j * 512 + 256 + t], SS);
        __syncthreads();
    }
}

// fused: inline BN-fold from branchAcc + affine + 8-slot sum + NHWC->NCHW transpose
__global__ void out_k(const unsigned short* __restrict__ P, const float* __restrict__ branchAcc,
                      const float* __restrict__ g0, const float* __restrict__ g1,
                      const float* __restrict__ g2, const float* __restrict__ g3,
                      const float* __restrict__ b0, const float* __restrict__ b1,
                      const float* __restrict__ b2, const float* __restrict__ b3,
                      float* __restrict__ out) {
    __shared__ float tile[64][132];
    int oh = blockIdx.x, ct = blockIdx.y, b = blockIdx.z;  // 64, 2, 2
    int t = threadIdx.x;
    int cg = t & 31, rt = t >> 5;  // 4 channels each, 8 row-threads
    int c0 = ct * 128 + cg * 4;
    float sc[4][4], sh[4];
#pragma unroll
    for (int k = 0; k < 4; k++) {
        int c = c0 + k;
        float shk = 0.f;
#pragma unroll
        for (int jj = 0; jj < 4; jj++) {
            const float* gamma = jj == 0 ? g0 : jj == 1 ? g1 : jj == 2 ? g2 : g3;
            const float* beta = jj == 0 ? b0 : jj == 1 ? b1 : jj == 2 ? b2 : b3;
            float sum = branchAcc[jj * 512 + c];
            float sumsq = branchAcc[jj * 512 + 256 + c];
            float mean = sum * (1.f / 8192.f);
            float var = sumsq * (1.f / 8192.f) - mean * mean;
            float rs = rsqrtf(var + 1e-5f);
            float scv = gamma[c] * rs;
            sc[jj][k] = scv;
            shk += beta[c] - mean * scv;
        }
        sh[k] = shk;
    }
#pragma unroll
    for (int it = 0; it < 8; it++) {
        int ow = rt * 8 + it;
        size_t row = (size_t)b * 4096 + oh * 64 + ow;
        const unsigned short* p = P + row * OUTC + c0;
        float a3k[4], a2k[4], a1k[4], a0k[4];
#pragma unroll
        for (int k = 0; k < 4; k++) { a3k[k] = a2k[k] = a1k[k] = a0k[k] = 0.f; }
#pragma unroll
        for (int zz = 0; zz < 8; zz++) {
            ushort4 u = *(const ushort4*)(p + (size_t)zz * M_ROWS * OUTC);
            float* a = zz < 4 ? a3k : zz < 6 ? a2k : (zz == 6 ? a1k : a0k);
            a[0] += bf2f(u.x);
            a[1] += bf2f(u.y);
            a[2] += bf2f(u.z);
            a[3] += bf2f(u.w);
        }
#pragma unroll
        for (int k = 0; k < 4; k++)
            tile[ow][cg * 4 + k] = sh[k] + a3k[k] * sc[3][k] + a2k[k] * sc[2][k] +
                                   a1k[k] * sc[1][k] + a0k[k] * sc[0][k];
    }
    __syncthreads();
    int owq = t & 15, cp = t >> 4;
#pragma unroll
    for (int pass = 0; pass < 8; pass++) {
        int c = pass * 16 + cp;
        float4 v;
        v.x = tile[owq * 4 + 0][c];
        v.y = tile[owq * 4 + 1][c];
        v.z = tile[owq * 4 + 2][c];
        v.w = tile[owq * 4 + 3][c];
        *(float4*)(out + (((size_t)b * OUTC + ct * 128 + c) * 64 + oh) * 64 + owq * 4) = v;
    }
}

extern "C" void kernel_launch(void* const* d_in, const int* in_sizes, int n_in,
                              void* d_out, int out_size, void* d_ws, size_t ws_size,
                              hipStream_t stream) {
    char* ws = (char*)d_ws;
    size_t off = 0;
    auto alloc = [&](size_t bytes) {
        void* p = ws + off;
        off = (off + bytes + 255) & ~(size_t)255;
        return p;
    };
    unsigned short* P = (unsigned short*)alloc((size_t)8 * M_ROWS * OUTC * 2);   // 33.6 MB
    unsigned short* wt = (unsigned short*)alloc((size_t)2304 * 960 * 2);         // 4.4 MB
    unsigned short* mapB = (unsigned short*)alloc((size_t)33800 * 960 * 2);      // 64.9 MB
    int* cnt32 = (int*)alloc((size_t)4 * 2 * HW * 4);                            // 0.5 MB
    float* branchAcc = (float*)alloc((size_t)4 * 512 * 4);                       // contiguous w/ cnt32
    unsigned short* list = (unsigned short*)alloc((size_t)4 * 2 * HW * MAXP * 2);// 8 MB

    hipMemsetAsync(cnt32, 0, (size_t)4 * 2 * HW * 4 + 4 * 512 * 4, stream);  // cnt32 + branchAcc

    fill_k<<<512, 256, 0, stream>>>(
        (const float*)d_in[1], (const float*)d_in[7], (const float*)d_in[13],
        (const float*)d_in[19],
        (const int*)d_in[2], (const int*)d_in[8], (const int*)d_in[14],
        (const int*)d_in[20], cnt32, list);
    prep_k<<<15844 + 8640, 256, 0, stream>>>(
        (const float*)d_in[0], (const float*)d_in[6], (const float*)d_in[12],
        (const float*)d_in[18], cnt32, list, mapB,
        (const float*)d_in[3], (const float*)d_in[9], (const float*)d_in[15],
        (const float*)d_in[21], wt);
    conv_mfma<<<1024, 256, 0, stream>>>(mapB, wt, P);
    statsC_k<<<512, 256, 0, stream>>>(P, branchAcc);
    out_k<<<dim3(64, 2, 2), 256, 0, stream>>>(P, branchAcc,
        (const float*)d_in[4], (const float*)d_in[10], (const float*)d_in[16],
        (const float*)d_in[22],
        (const float*)d_in[5], (const float*)d_in[11], (const float*)d_in[17],
        (const float*)d_in[23], (float*)d_out);
}